// Round 2
// baseline (301.656 us; speedup 1.0000x reference)
//
#include <hip/hip_runtime.h>
#include <hip/hip_bf16.h>

using bf16 = __hip_bfloat16;
typedef __attribute__((ext_vector_type(8))) short shortx8;  // 8 bf16 = 4 VGPRs (MFMA A/B frag)
typedef __attribute__((ext_vector_type(4))) float f32x4;    // MFMA C/D frag

#define SEQ 8192
#define DM 1024
#define NH 16
#define DH 64
#define CHUNK 64
#define NC (SEQ / CHUNK)   // 128

// ---------------------------------------------------------------------------
// fp32 -> bf16 conversion (memory-bound, trivial)
// ---------------------------------------------------------------------------
__global__ __launch_bounds__(256) void f32_to_bf16_kernel(const float* __restrict__ in,
                                                          bf16* __restrict__ out, int n) {
    int i = (blockIdx.x * 256 + threadIdx.x) * 4;
    if (i >= n) return;
    float4 f = *(const float4*)(in + i);
    out[i + 0] = __float2bfloat16(f.x);
    out[i + 1] = __float2bfloat16(f.y);
    out[i + 2] = __float2bfloat16(f.z);
    out[i + 3] = __float2bfloat16(f.w);
}

// ---------------------------------------------------------------------------
// NT GEMM: C[M,N] = A[M,K] * B[N,K]^T, bf16 in, fp32 accumulate.
// 128x128 tile, BK=64, 256 threads (4 waves, each a 64x64 subtile of
// 4x4 mfma_f32_16x16x32_bf16). LDS rows padded +8 bf16.
// MODE 0: act=elu(x)+1 -> fp32   (K projection; feeds scalar reduction only)
// MODE 1: plain -> fp32          (V projection; feeds scan only)
// MODE 2: +bias, tanh-gelu -> bf16  (MLP layer 1)
// MODE 3: +bias -> fp32          (MLP layer 2, final output)
// ---------------------------------------------------------------------------
#define BM 128
#define BN 128
#define BK 64
#define LDSK (BK + 8)   // 72 elems = 144 B row stride

template <int MODE>
__global__ __launch_bounds__(256) void gemm_nt(const bf16* __restrict__ A,
                                               const bf16* __restrict__ B,
                                               void* __restrict__ Cv,
                                               const float* __restrict__ bias,
                                               int M, int N, int K) {
    __shared__ bf16 As[BM][LDSK];
    __shared__ bf16 Bs[BN][LDSK];

    const int tid  = threadIdx.x;
    const int bm   = blockIdx.y * BM;
    const int bn   = blockIdx.x * BN;
    const int wave = tid >> 6;
    const int lane = tid & 63;
    const int wm   = (wave >> 1) * 64;
    const int wn   = (wave & 1) * 64;
    const int quad = lane >> 4;
    const int m16  = lane & 15;

    f32x4 acc[4][4];
    #pragma unroll
    for (int i = 0; i < 4; ++i)
        #pragma unroll
        for (int j = 0; j < 4; ++j)
            #pragma unroll
            for (int r = 0; r < 4; ++r) acc[i][j][r] = 0.f;

    const int srow = tid >> 3;          // 0..31
    const int scol = (tid & 7) << 3;    // 0,8,..,56

    for (int k0 = 0; k0 < K; k0 += BK) {
        #pragma unroll
        for (int r = 0; r < 4; ++r) {
            int row = srow + 32 * r;
            *(float4*)&As[row][scol] = *(const float4*)(A + (size_t)(bm + row) * K + k0 + scol);
            *(float4*)&Bs[row][scol] = *(const float4*)(B + (size_t)(bn + row) * K + k0 + scol);
        }
        __syncthreads();

        #pragma unroll
        for (int kk = 0; kk < BK; kk += 32) {
            shortx8 af[4], bfr[4];
            #pragma unroll
            for (int i = 0; i < 4; ++i)
                af[i] = *(const shortx8*)&As[wm + i * 16 + m16][kk + quad * 8];
            #pragma unroll
            for (int j = 0; j < 4; ++j)
                bfr[j] = *(const shortx8*)&Bs[wn + j * 16 + m16][kk + quad * 8];
            #pragma unroll
            for (int i = 0; i < 4; ++i)
                #pragma unroll
                for (int j = 0; j < 4; ++j)
                    acc[i][j] = __builtin_amdgcn_mfma_f32_16x16x32_bf16(af[i], bfr[j], acc[i][j], 0, 0, 0);
        }
        __syncthreads();
    }

    // epilogue: C/D layout col = lane&15, row = quad*4 + reg (verified m89/m91)
    #pragma unroll
    for (int i = 0; i < 4; ++i) {
        int row0 = bm + wm + i * 16 + quad * 4;
        #pragma unroll
        for (int j = 0; j < 4; ++j) {
            int col = bn + wn + j * 16 + m16;
            #pragma unroll
            for (int r = 0; r < 4; ++r) {
                float v = acc[i][j][r];
                size_t o = (size_t)(row0 + r) * N + col;
                if (MODE == 0) {            // act(x) = elu(x)+1, fp32 out
                    v = v > 0.f ? v + 1.f : expf(v);
                    ((float*)Cv)[o] = v;
                } else if (MODE == 1) {     // plain fp32 out
                    ((float*)Cv)[o] = v;
                } else if (MODE == 2) {     // bias + tanh-gelu -> bf16
                    v += bias[col];
                    float g = 0.5f * v * (1.f + tanhf(0.7978845608028654f * (v + 0.044715f * v * v * v)));
                    ((bf16*)Cv)[o] = __float2bfloat16(g);
                } else {                    // bias + fp32 store (final)
                    v += bias[col];
                    ((float*)Cv)[o] = v;
                }
            }
        }
    }
}

// ---------------------------------------------------------------------------
// kappa[h][t] = sum_d ka[t][h*64+d]  (one wave per (t,h) row of 64)
// ---------------------------------------------------------------------------
__global__ __launch_bounds__(256) void kappa_reduce(const float* __restrict__ ka,
                                                    float* __restrict__ kappa) {
    const int p = blockIdx.x * 4 + (threadIdx.x >> 6);  // pair index t*NH+h
    const int t = p >> 4;
    const int h = p & 15;
    const int d = threadIdx.x & 63;
    float v = ka[(size_t)t * DM + h * 64 + d];
    #pragma unroll
    for (int off = 32; off > 0; off >>= 1) v += __shfl_down(v, off);
    if (d == 0) kappa[(size_t)h * SEQ + t] = v;
}

// ---------------------------------------------------------------------------
// Phase A: per (head, chunk): num_c[v] = sum_t kappa_t * V[t][v]; den_c = sum_t kappa_t
// ---------------------------------------------------------------------------
__global__ __launch_bounds__(256) void chunk_sums(const float* __restrict__ vf,
                                                  const float* __restrict__ kappa,
                                                  float* __restrict__ numbuf,
                                                  float* __restrict__ denbuf) {
    const int h = blockIdx.x, c = blockIdx.y;
    __shared__ float Ksh[64];
    __shared__ float part[4][64];
    const int tid = threadIdx.x;

    if (tid < 64) Ksh[tid] = kappa[(size_t)h * SEQ + c * 64 + tid];
    __syncthreads();

    const int d  = tid & 63;
    const int tq = tid >> 6;
    float acc = 0.f;
    #pragma unroll
    for (int tt = 0; tt < 16; ++tt) {
        int t = tq * 16 + tt;
        acc += Ksh[t] * vf[(size_t)(c * 64 + t) * DM + h * 64 + d];
    }
    part[tq][d] = acc;
    __syncthreads();

    if (tid < 64) {
        float s = part[0][tid] + part[1][tid] + part[2][tid] + part[3][tid];
        numbuf[((size_t)h * NC + c) * 64 + tid] = s;
        float kv = Ksh[tid];
        #pragma unroll
        for (int off = 32; off > 0; off >>= 1) kv += __shfl_down(kv, off);
        if (tid == 0) denbuf[(size_t)h * NC + c] = kv;
    }
}

// ---------------------------------------------------------------------------
// Phase B: exclusive prefix over chunks (one wave per head, thread d owns dim d)
// ---------------------------------------------------------------------------
__global__ __launch_bounds__(64) void prefix_state(float* __restrict__ numbuf,
                                                   float* __restrict__ denbuf) {
    const int h = blockIdx.x, d = threadIdx.x;
    float run = 0.f, drun = 0.f;
    for (int c = 0; c < NC; ++c) {
        size_t idx = (size_t)h * NC + c;
        float cur = numbuf[idx * 64 + d];
        numbuf[idx * 64 + d] = run;
        run += cur;
        if (d == 0) {
            float dc = denbuf[idx];
            denbuf[idx] = drun;
            drun += dc;
        }
    }
}

// ---------------------------------------------------------------------------
// Phase C: out[t][v] = (N_excl[v] + sum_{i<=t} kappa_i V[i][v]) /
//                     (D_excl    + sum_{i<=t} kappa_i)            -> bf16
// Thread (t = tid>>2, v0 = (tid&3)*16) owns 16 outputs.
// ---------------------------------------------------------------------------
__global__ __launch_bounds__(256) void chunk_out(const float* __restrict__ vf,
                                                 const float* __restrict__ kappa,
                                                 const float* __restrict__ numbuf,
                                                 const float* __restrict__ denbuf,
                                                 bf16* __restrict__ out) {
    const int h = blockIdx.x, c = blockIdx.y;
    __shared__ float Ksh[64];
    __shared__ float Vs[64][64];
    const int tid = threadIdx.x;

    if (tid < 64) Ksh[tid] = kappa[(size_t)h * SEQ + c * 64 + tid];
    for (int idx = tid; idx < 64 * 64; idx += 256) {
        int r = idx >> 6, d = idx & 63;
        Vs[r][d] = vf[(size_t)(c * 64 + r) * DM + h * 64 + d];
    }
    __syncthreads();

    const int t  = tid >> 2;
    const int v0 = (tid & 3) << 4;
    const size_t bidx = (size_t)h * NC + c;

    float den = denbuf[bidx];
    float num[16];
    #pragma unroll
    for (int jj = 0; jj < 4; ++jj) {
        float4 n4 = *(const float4*)&numbuf[bidx * 64 + v0 + jj * 4];
        num[jj * 4 + 0] = n4.x; num[jj * 4 + 1] = n4.y;
        num[jj * 4 + 2] = n4.z; num[jj * 4 + 3] = n4.w;
    }

    for (int i = 0; i <= t; ++i) {
        float s = Ksh[i];
        den += s;
        #pragma unroll
        for (int jj = 0; jj < 4; ++jj) {
            float4 v4 = *(const float4*)&Vs[i][v0 + jj * 4];
            num[jj * 4 + 0] += s * v4.x; num[jj * 4 + 1] += s * v4.y;
            num[jj * 4 + 2] += s * v4.z; num[jj * 4 + 3] += s * v4.w;
        }
    }

    const float inv = 1.0f / den;
    size_t og = (size_t)(c * 64 + t) * DM + h * 64 + v0;
    #pragma unroll
    for (int j = 0; j < 16; ++j) out[og + j] = __float2bfloat16(num[j] * inv);
}

// ---------------------------------------------------------------------------
extern "C" void kernel_launch(void* const* d_in, const int* in_sizes, int n_in,
                              void* d_out, int out_size, void* d_ws, size_t ws_size,
                              hipStream_t stream) {
    const float* xs = (const float*)d_in[0];
    // d_in[1] = wq — provably unused: the reference's 'hkv,hq->hv' / 'hk,hq->h'
    // einsums sum k and q independently, so the Sum(qa) factor cancels in sq/zq.
    const float* wk = (const float*)d_in[2];
    const float* wv = (const float*)d_in[3];
    const float* w1 = (const float*)d_in[4];
    const float* b1 = (const float*)d_in[5];
    const float* w2 = (const float*)d_in[6];
    const float* b2 = (const float*)d_in[7];
    float* y = (float*)d_out;

    char* base = (char*)d_ws;
    size_t off = 0;
    auto alloc = [&](size_t b) -> char* {
        char* p = base + off;
        off += (b + 255) & ~(size_t)255;
        return p;
    };

    const size_t NMAT = (size_t)SEQ * DM;      // 8.39M
    const size_t NW   = (size_t)DM * DM;       // 1.05M
    bf16*  xsb   = (bf16*)alloc(NMAT * 2);
    bf16*  wkb   = (bf16*)alloc(NW * 2);
    bf16*  wvb   = (bf16*)alloc(NW * 2);
    bf16*  w1b   = (bf16*)alloc(NW * 2);
    bf16*  w2b   = (bf16*)alloc(NW * 2);
    float* kaf   = (float*)alloc(NMAT * 4);    // act(K) fp32
    float* vf    = (float*)alloc(NMAT * 4);    // V fp32
    float* kappa = (float*)alloc((size_t)NH * SEQ * 4);
    float* numbuf = (float*)alloc((size_t)NH * NC * 64 * 4);
    float* denbuf = (float*)alloc((size_t)NH * NC * 4);
    bf16*  outb  = (bf16*)alloc(NMAT * 2);
    bf16*  hb    = (bf16*)alloc(NMAT * 2);
    // total ~121 MB

    // 1. convert inputs to bf16 (wq skipped — unused)
    f32_to_bf16_kernel<<<(int)(NMAT / 4 / 256), 256, 0, stream>>>(xs, xsb, (int)NMAT);
    f32_to_bf16_kernel<<<(int)(NW / 4 / 256), 256, 0, stream>>>(wk, wkb, (int)NW);
    f32_to_bf16_kernel<<<(int)(NW / 4 / 256), 256, 0, stream>>>(wv, wvb, (int)NW);
    f32_to_bf16_kernel<<<(int)(NW / 4 / 256), 256, 0, stream>>>(w1, w1b, (int)NW);
    f32_to_bf16_kernel<<<(int)(NW / 4 / 256), 256, 0, stream>>>(w2, w2b, (int)NW);

    // 2. K,V projections (act fused into K epilogue, fp32 outputs)
    dim3 ggrid(DM / BN, SEQ / BM);   // (8, 64)
    gemm_nt<0><<<ggrid, 256, 0, stream>>>(xsb, wkb, kaf, nullptr, SEQ, DM, DM);
    gemm_nt<1><<<ggrid, 256, 0, stream>>>(xsb, wvb, vf, nullptr, SEQ, DM, DM);

    // 3. scalar-weighted running average (the degenerate linear-attention scan)
    kappa_reduce<<<SEQ * NH / 4, 256, 0, stream>>>(kaf, kappa);
    chunk_sums<<<dim3(NH, NC), 256, 0, stream>>>(vf, kappa, numbuf, denbuf);
    prefix_state<<<NH, 64, 0, stream>>>(numbuf, denbuf);
    chunk_out<<<dim3(NH, NC), 256, 0, stream>>>(vf, kappa, numbuf, denbuf, outb);

    // 4. MLP
    gemm_nt<2><<<ggrid, 256, 0, stream>>>(outb, w1b, hb, b1, SEQ, DM, DM);
    gemm_nt<3><<<ggrid, 256, 0, stream>>>(hb, w2b, y, b2, SEQ, DM, DM);
}